// Round 7
// baseline (55.611 us; speedup 1.0000x reference)
//
#include <hip/hip_runtime.h>

namespace {

constexpr int kB  = 8;
constexpr int kCF = 32;
constexpr int kCP = 4;
constexpr int kS  = 64;
constexpr int kL  = 32;
constexpr int kPlane = kS * kS;                         // 4096
constexpr long long kChStride = (long long)kS * kPlane; // 262144 floats per channel
constexpr int kMCos = kL * kPlane;                      // 131072 cos positions / sample
constexpr int kKlElems = kCP * kL * kPlane;             // 524288 kl floats / sample
constexpr int kGrid = 1024;                             // 128 uniform blocks per sample
constexpr int kBlocksPerB = kGrid / kB;                 // 128
constexpr float kClampEps = 1e-6f;
constexpr float kCosEps = 1e-8f;
constexpr float kCosScale = 1.0f / (float)((long long)kB * kMCos);
constexpr float kKlScale  = 0.3f / (float)kB;

// Native clang vector type (__builtin_nontemporal_load rejects the
// HIP_vector_type structs).
typedef float floatx4 __attribute__((ext_vector_type(4)));

__device__ __forceinline__ floatx4 nt_load4(const float* p) {
  return __builtin_nontemporal_load(reinterpret_cast<const floatx4*>(p));
}

__device__ __forceinline__ float block_reduce_sum(float v) {
  #pragma unroll
  for (int off = 32; off > 0; off >>= 1) v += __shfl_down(v, off, 64);
  __shared__ float smem[4];
  const int lane = threadIdx.x & 63;
  const int wid  = threadIdx.x >> 6;
  if (lane == 0) smem[wid] = v;
  __syncthreads();
  float r = 0.f;
  if (threadIdx.x == 0) r = smem[0] + smem[1] + smem[2] + smem[3];
  __syncthreads();
  return r;
}

__device__ __forceinline__ float kl_term(float sv, float tv) {
  const float sc = fminf(fmaxf(sv, kClampEps), 1.f - kClampEps);
  const float tc = fminf(fmaxf(tv, kClampEps), 1.f - kClampEps);
  return tc * (__logf(tc) - __logf(sc));
}

// Uniform fused kernel, float4 (1 KB/wave-instr) on every stream.
// 1024 identical blocks: each covers 1024 cos positions (32 ch x 2 tensors,
// 256 KB) + 4096 KL floats (2 tensors, 32 KB). partial[blk] pre-scaled;
// loss = 1 + sum(partial).
__global__ __launch_bounds__(256) void fused_main(
    const float* __restrict__ sf, const float* __restrict__ tf,
    const float* __restrict__ sp, const float* __restrict__ tp,
    const int* __restrict__ cur_start, const int* __restrict__ adj_start,
    float* __restrict__ partial) {
  const int blk = blockIdx.x;
  const int b   = blk >> 7;                // sample (128 blocks per sample)
  const int i   = blk & (kBlocksPerB - 1);
  const int cs  = cur_start[b];
  const int as  = adj_start[b];

  // ---- cosine part: positions [i*1024, i*1024+1024) of sample b ----
  float cosLocal;
  {
    const int posbase = i << 10;                       // i*1024
    const int dd  = posbase >> 12;                     // constant per block
    const int rem = (posbase & (kPlane - 1)) + (int)threadIdx.x * 4;
    const float* s0 = sf + ((long long)b * kCF * kS + (cs + dd)) * kPlane + rem;
    const float* t0 = tf + ((long long)b * kCF * kS + (as + dd)) * kPlane + rem;
    floatx4 dot = {0.f, 0.f, 0.f, 0.f};
    floatx4 na  = {0.f, 0.f, 0.f, 0.f};
    floatx4 nb  = {0.f, 0.f, 0.f, 0.f};
    #pragma unroll 8
    for (int c = 0; c < kCF; ++c) {
      const floatx4 a = nt_load4(s0 + c * kChStride);
      const floatx4 t = nt_load4(t0 + c * kChStride);
      dot += a * t;
      na  += a * a;
      nb  += t * t;
    }
    cosLocal =
        dot.x / (fmaxf(sqrtf(na.x), kCosEps) * fmaxf(sqrtf(nb.x), kCosEps)) +
        dot.y / (fmaxf(sqrtf(na.y), kCosEps) * fmaxf(sqrtf(nb.y), kCosEps)) +
        dot.z / (fmaxf(sqrtf(na.z), kCosEps) * fmaxf(sqrtf(nb.z), kCosEps)) +
        dot.w / (fmaxf(sqrtf(na.w), kCosEps) * fmaxf(sqrtf(nb.w), kCosEps));
  }

  // ---- KL part: floats [i*4096, i*4096+4096) of sample b's slice ----
  // i*4096 is plane-aligned: c = i/32, plane index = i%32, rem = 0.
  float klLocal = 0.f;
  {
    const int c   = i >> 5;                            // prob channel 0..3
    const int ddk = i & 31;                            // plane within slice
    const float* sb = sp + ((long long)(b * kCP + c) * kS + (cs + ddk)) * kPlane;
    const float* tb = tp + ((long long)(b * kCP + c) * kS + (as + ddk)) * kPlane;
    #pragma unroll
    for (int h = 0; h < 4; ++h) {
      const int off = h * 1024 + (int)threadIdx.x * 4;
      const floatx4 s4 = nt_load4(sb + off);
      const floatx4 t4 = nt_load4(tb + off);
      klLocal += kl_term(s4.x, t4.x) + kl_term(s4.y, t4.y) +
                 kl_term(s4.z, t4.z) + kl_term(s4.w, t4.w);
    }
  }

  const float local = -cosLocal * kCosScale + klLocal * kKlScale;
  const float s = block_reduce_sum(local);
  if (threadIdx.x == 0) partial[blk] = s;
}

// Single block: loss = 1 + sum(partial[0..kGrid)).
__global__ __launch_bounds__(256) void final_kernel(
    const float* __restrict__ partial, float* __restrict__ out) {
  float acc = 0.f;
  for (int i = threadIdx.x; i < kGrid; i += 256) acc += partial[i];
  const float tot = block_reduce_sum(acc);
  if (threadIdx.x == 0) out[0] = 1.f + tot;
}

}  // namespace

extern "C" void kernel_launch(void* const* d_in, const int* in_sizes, int n_in,
                              void* d_out, int out_size, void* d_ws, size_t ws_size,
                              hipStream_t stream) {
  const float* sf = (const float*)d_in[0];
  const float* tf = (const float*)d_in[1];
  const float* sp = (const float*)d_in[2];
  const float* tp = (const float*)d_in[3];
  const int* cur_start = (const int*)d_in[4];
  const int* adj_start = (const int*)d_in[5];
  float* out = (float*)d_out;
  float* partial = (float*)d_ws;  // kGrid * 4 = 4096 bytes

  fused_main<<<kGrid, 256, 0, stream>>>(
      sf, tf, sp, tp, cur_start, adj_start, partial);
  final_kernel<<<1, 256, 0, stream>>>(partial, out);
}

// Round 8
// 51.938 us; speedup vs baseline: 1.0707x; 1.0707x over previous
//
#include <hip/hip_runtime.h>

namespace {

constexpr int kB  = 8;
constexpr int kCF = 32;
constexpr int kCP = 4;
constexpr int kS  = 64;
constexpr int kL  = 32;
constexpr int kPlane = kS * kS;                         // 4096
constexpr long long kChStride = (long long)kS * kPlane; // 262144 floats per channel
constexpr int kMCos = kL * kPlane;                      // 131072 cos positions / sample
constexpr int kGrid = 2048;                             // 256 blocks/sample = exact co-residency (8 blk/CU)
constexpr int kBlocksPerB = kGrid / kB;                 // 256
constexpr float kClampEps = 1e-6f;
constexpr float kCosEps = 1e-8f;
constexpr float kCosScale = 1.0f / (float)((long long)kB * kMCos);
constexpr float kKlScale  = 0.3f / (float)kB;

// Native clang vector types (__builtin_nontemporal_load rejects the
// HIP_vector_type structs).
typedef float floatx2 __attribute__((ext_vector_type(2)));
typedef float floatx4 __attribute__((ext_vector_type(4)));

__device__ __forceinline__ floatx2 nt_load2(const float* p) {
  return __builtin_nontemporal_load(reinterpret_cast<const floatx2*>(p));
}
__device__ __forceinline__ floatx4 nt_load4(const float* p) {
  return __builtin_nontemporal_load(reinterpret_cast<const floatx4*>(p));
}

__device__ __forceinline__ float block_reduce_sum(float v) {
  #pragma unroll
  for (int off = 32; off > 0; off >>= 1) v += __shfl_down(v, off, 64);
  __shared__ float smem[4];
  const int lane = threadIdx.x & 63;
  const int wid  = threadIdx.x >> 6;
  if (lane == 0) smem[wid] = v;
  __syncthreads();
  float r = 0.f;
  if (threadIdx.x == 0) r = smem[0] + smem[1] + smem[2] + smem[3];
  __syncthreads();
  return r;
}

__device__ __forceinline__ float kl_term(float sv, float tv) {
  const float sc = fminf(fmaxf(sv, kClampEps), 1.f - kClampEps);
  const float tc = fminf(fmaxf(tv, kClampEps), 1.f - kClampEps);
  return tc * (__logf(tc) - __logf(sc));
}

// Round-6 structure (best: 53.4 us): 2048 uniform blocks, float2 cos +
// float4 KL, all nontemporal. New: cos channel loop in explicit batches of
// 8 channels x 2 tensors -> 16 loads issued back-to-back (named registers,
// static indexing) before any FMA, forcing ~16 outstanding loads per wave
// instead of compiler-chosen ~4-6. VGPR ~55 stays under the 64 ceiling for
// 8 waves/SIMD, so occupancy is unchanged at 32 waves/CU.
__global__ __launch_bounds__(256) void fused_main(
    const float* __restrict__ sf, const float* __restrict__ tf,
    const float* __restrict__ sp, const float* __restrict__ tp,
    const int* __restrict__ cur_start, const int* __restrict__ adj_start,
    float* __restrict__ partial) {
  const int blk = blockIdx.x;
  const int b   = blk >> 8;                // sample (256 blocks per sample)
  const int i   = blk & (kBlocksPerB - 1);
  const int cs  = cur_start[b];
  const int as  = adj_start[b];

  // ---- cosine part: positions [i*512, i*512+512) of sample b ----
  float cosLocal;
  {
    const int posbase = i << 9;                        // i*512
    const int dd  = posbase >> 12;                     // constant per block
    const int rem = (posbase & (kPlane - 1)) + (int)threadIdx.x * 2;
    const float* s0 = sf + ((long long)b * kCF * kS + (cs + dd)) * kPlane + rem;
    const float* t0 = tf + ((long long)b * kCF * kS + (as + dd)) * kPlane + rem;
    floatx2 dot = {0.f, 0.f};
    floatx2 na  = {0.f, 0.f};
    floatx2 nb  = {0.f, 0.f};
    #pragma unroll
    for (int cb = 0; cb < kCF; cb += 8) {
      floatx2 a0 = nt_load2(s0 + (cb + 0) * kChStride);
      floatx2 a1 = nt_load2(s0 + (cb + 1) * kChStride);
      floatx2 a2 = nt_load2(s0 + (cb + 2) * kChStride);
      floatx2 a3 = nt_load2(s0 + (cb + 3) * kChStride);
      floatx2 a4 = nt_load2(s0 + (cb + 4) * kChStride);
      floatx2 a5 = nt_load2(s0 + (cb + 5) * kChStride);
      floatx2 a6 = nt_load2(s0 + (cb + 6) * kChStride);
      floatx2 a7 = nt_load2(s0 + (cb + 7) * kChStride);
      floatx2 t0v = nt_load2(t0 + (cb + 0) * kChStride);
      floatx2 t1v = nt_load2(t0 + (cb + 1) * kChStride);
      floatx2 t2v = nt_load2(t0 + (cb + 2) * kChStride);
      floatx2 t3v = nt_load2(t0 + (cb + 3) * kChStride);
      floatx2 t4v = nt_load2(t0 + (cb + 4) * kChStride);
      floatx2 t5v = nt_load2(t0 + (cb + 5) * kChStride);
      floatx2 t6v = nt_load2(t0 + (cb + 6) * kChStride);
      floatx2 t7v = nt_load2(t0 + (cb + 7) * kChStride);
      dot += a0 * t0v; na += a0 * a0; nb += t0v * t0v;
      dot += a1 * t1v; na += a1 * a1; nb += t1v * t1v;
      dot += a2 * t2v; na += a2 * a2; nb += t2v * t2v;
      dot += a3 * t3v; na += a3 * a3; nb += t3v * t3v;
      dot += a4 * t4v; na += a4 * a4; nb += t4v * t4v;
      dot += a5 * t5v; na += a5 * a5; nb += t5v * t5v;
      dot += a6 * t6v; na += a6 * a6; nb += t6v * t6v;
      dot += a7 * t7v; na += a7 * a7; nb += t7v * t7v;
    }
    cosLocal =
        dot.x / (fmaxf(sqrtf(na.x), kCosEps) * fmaxf(sqrtf(nb.x), kCosEps)) +
        dot.y / (fmaxf(sqrtf(na.y), kCosEps) * fmaxf(sqrtf(nb.y), kCosEps));
  }

  // ---- KL part: floats [i*2048, i*2048+2048) of sample b's slice ----
  float klLocal = 0.f;
  {
    const int fbase = i << 11;                         // i*2048
    const int c   = fbase >> 17;                       // prob channel 0..3
    const int m   = fbase & (kMCos - 1);
    const int ddk = m >> 12;                           // constant per block
    const int remk = m & (kPlane - 1);                 // 0 or 2048
    const float* sb = sp + ((long long)(b * kCP + c) * kS + (cs + ddk)) * kPlane + remk;
    const float* tb = tp + ((long long)(b * kCP + c) * kS + (as + ddk)) * kPlane + remk;
    const int off0 = (int)threadIdx.x * 4;
    const floatx4 s4a = nt_load4(sb + off0);
    const floatx4 t4a = nt_load4(tb + off0);
    const floatx4 s4b = nt_load4(sb + off0 + 1024);
    const floatx4 t4b = nt_load4(tb + off0 + 1024);
    klLocal = kl_term(s4a.x, t4a.x) + kl_term(s4a.y, t4a.y) +
              kl_term(s4a.z, t4a.z) + kl_term(s4a.w, t4a.w) +
              kl_term(s4b.x, t4b.x) + kl_term(s4b.y, t4b.y) +
              kl_term(s4b.z, t4b.z) + kl_term(s4b.w, t4b.w);
  }

  const float local = -cosLocal * kCosScale + klLocal * kKlScale;
  const float s = block_reduce_sum(local);
  if (threadIdx.x == 0) partial[blk] = s;
}

// Single block: loss = 1 + sum(partial[0..kGrid)).
__global__ __launch_bounds__(256) void final_kernel(
    const float* __restrict__ partial, float* __restrict__ out) {
  float acc = 0.f;
  for (int i = threadIdx.x; i < kGrid; i += 256) acc += partial[i];
  const float tot = block_reduce_sum(acc);
  if (threadIdx.x == 0) out[0] = 1.f + tot;
}

}  // namespace

extern "C" void kernel_launch(void* const* d_in, const int* in_sizes, int n_in,
                              void* d_out, int out_size, void* d_ws, size_t ws_size,
                              hipStream_t stream) {
  const float* sf = (const float*)d_in[0];
  const float* tf = (const float*)d_in[1];
  const float* sp = (const float*)d_in[2];
  const float* tp = (const float*)d_in[3];
  const int* cur_start = (const int*)d_in[4];
  const int* adj_start = (const int*)d_in[5];
  float* out = (float*)d_out;
  float* partial = (float*)d_ws;  // kGrid * 4 = 8192 bytes

  fused_main<<<kGrid, 256, 0, stream>>>(
      sf, tf, sp, tp, cur_start, adj_start, partial);
  final_kernel<<<1, 256, 0, stream>>>(partial, out);
}

// Round 9
// 49.972 us; speedup vs baseline: 1.1129x; 1.0394x over previous
//
#include <hip/hip_runtime.h>

namespace {

constexpr int kB  = 8;
constexpr int kCF = 32;
constexpr int kCP = 4;
constexpr int kS  = 64;
constexpr int kL  = 32;
constexpr int kPlane = kS * kS;                         // 4096
constexpr long long kChStride = (long long)kS * kPlane; // 262144 floats per channel
constexpr int kMCos = kL * kPlane;                      // 131072 cos positions / sample
constexpr int kGrid = 2048;                             // 256 blocks/sample = exact co-residency (8 blk/CU)
constexpr int kBlocksPerB = kGrid / kB;                 // 256
constexpr float kClampEps = 1e-6f;
constexpr float kCosEps = 1e-8f;
constexpr float kCosScale = 1.0f / (float)((long long)kB * kMCos);
constexpr float kKlScale  = 0.3f / (float)kB;

// Native clang vector types (__builtin_nontemporal_load rejects the
// HIP_vector_type structs).
typedef float floatx2 __attribute__((ext_vector_type(2)));
typedef float floatx4 __attribute__((ext_vector_type(4)));

__device__ __forceinline__ floatx2 nt_load2(const float* p) {
  return __builtin_nontemporal_load(reinterpret_cast<const floatx2*>(p));
}
__device__ __forceinline__ floatx4 nt_load4(const float* p) {
  return __builtin_nontemporal_load(reinterpret_cast<const floatx4*>(p));
}

__device__ __forceinline__ float kl_term(float sv, float tv) {
  const float sc = fminf(fmaxf(sv, kClampEps), 1.f - kClampEps);
  const float tc = fminf(fmaxf(tv, kClampEps), 1.f - kClampEps);
  return tc * (__logf(tc) - __logf(sc));
}

// One batch of 8 channels x 2 tensors: 16 nt loads issued back-to-back
// (named registers, static indexing), then 24 packed FMAs.
__device__ __forceinline__ void cos_batch(
    const float* __restrict__ s0, const float* __restrict__ t0, int cb,
    floatx2& dot, floatx2& na, floatx2& nb) {
  floatx2 a0 = nt_load2(s0 + (cb + 0) * kChStride);
  floatx2 a1 = nt_load2(s0 + (cb + 1) * kChStride);
  floatx2 a2 = nt_load2(s0 + (cb + 2) * kChStride);
  floatx2 a3 = nt_load2(s0 + (cb + 3) * kChStride);
  floatx2 a4 = nt_load2(s0 + (cb + 4) * kChStride);
  floatx2 a5 = nt_load2(s0 + (cb + 5) * kChStride);
  floatx2 a6 = nt_load2(s0 + (cb + 6) * kChStride);
  floatx2 a7 = nt_load2(s0 + (cb + 7) * kChStride);
  floatx2 t0v = nt_load2(t0 + (cb + 0) * kChStride);
  floatx2 t1v = nt_load2(t0 + (cb + 1) * kChStride);
  floatx2 t2v = nt_load2(t0 + (cb + 2) * kChStride);
  floatx2 t3v = nt_load2(t0 + (cb + 3) * kChStride);
  floatx2 t4v = nt_load2(t0 + (cb + 4) * kChStride);
  floatx2 t5v = nt_load2(t0 + (cb + 5) * kChStride);
  floatx2 t6v = nt_load2(t0 + (cb + 6) * kChStride);
  floatx2 t7v = nt_load2(t0 + (cb + 7) * kChStride);
  dot += a0 * t0v; na += a0 * a0; nb += t0v * t0v;
  dot += a1 * t1v; na += a1 * a1; nb += t1v * t1v;
  dot += a2 * t2v; na += a2 * a2; nb += t2v * t2v;
  dot += a3 * t3v; na += a3 * a3; nb += t3v * t3v;
  dot += a4 * t4v; na += a4 * a4; nb += t4v * t4v;
  dot += a5 * t5v; na += a5 * a5; nb += t5v * t5v;
  dot += a6 * t6v; na += a6 * a6; nb += t6v * t6v;
  dot += a7 * t7v; na += a7 * a7; nb += t7v * t7v;
}

// 2048 uniform blocks (exact co-residency), float2 cos + float4 KL, all
// nontemporal. KL loads are issued between cos batches 2 and 3 so their
// HBM latency hides under the remaining ~1600 cycles of cos work instead
// of forming the block tail. Peak live VGPR ~62 < 64 -> 8 waves/SIMD kept.
__global__ __launch_bounds__(256) void fused_main(
    const float* __restrict__ sf, const float* __restrict__ tf,
    const float* __restrict__ sp, const float* __restrict__ tp,
    const int* __restrict__ cur_start, const int* __restrict__ adj_start,
    float* __restrict__ partial) {
  const int blk = blockIdx.x;
  const int b   = blk >> 8;                // sample (256 blocks per sample)
  const int i   = blk & (kBlocksPerB - 1);
  const int cs  = cur_start[b];
  const int as  = adj_start[b];

  // cos addresses: positions [i*512, i*512+512) of sample b
  const int posbase = i << 9;
  const int dd  = posbase >> 12;
  const int rem = (posbase & (kPlane - 1)) + (int)threadIdx.x * 2;
  const float* s0 = sf + ((long long)b * kCF * kS + (cs + dd)) * kPlane + rem;
  const float* t0 = tf + ((long long)b * kCF * kS + (as + dd)) * kPlane + rem;

  // KL addresses: floats [i*2048, i*2048+2048) of sample b's slice
  const int fbase = i << 11;
  const int c   = fbase >> 17;
  const int m   = fbase & (kMCos - 1);
  const int ddk = m >> 12;
  const int remk = m & (kPlane - 1);
  const float* sb = sp + ((long long)(b * kCP + c) * kS + (cs + ddk)) * kPlane + remk;
  const float* tb = tp + ((long long)(b * kCP + c) * kS + (as + ddk)) * kPlane + remk;
  const int off0 = (int)threadIdx.x * 4;

  floatx2 dot = {0.f, 0.f};
  floatx2 na  = {0.f, 0.f};
  floatx2 nb  = {0.f, 0.f};
  cos_batch(s0, t0, 0, dot, na, nb);
  cos_batch(s0, t0, 8, dot, na, nb);
  // hoisted KL loads: latency overlaps cos batches 3-4
  const floatx4 s4a = nt_load4(sb + off0);
  const floatx4 t4a = nt_load4(tb + off0);
  const floatx4 s4b = nt_load4(sb + off0 + 1024);
  const floatx4 t4b = nt_load4(tb + off0 + 1024);
  cos_batch(s0, t0, 16, dot, na, nb);
  cos_batch(s0, t0, 24, dot, na, nb);

  const float cosLocal =
      dot.x / (fmaxf(sqrtf(na.x), kCosEps) * fmaxf(sqrtf(nb.x), kCosEps)) +
      dot.y / (fmaxf(sqrtf(na.y), kCosEps) * fmaxf(sqrtf(nb.y), kCosEps));

  const float klLocal =
      kl_term(s4a.x, t4a.x) + kl_term(s4a.y, t4a.y) +
      kl_term(s4a.z, t4a.z) + kl_term(s4a.w, t4a.w) +
      kl_term(s4b.x, t4b.x) + kl_term(s4b.y, t4b.y) +
      kl_term(s4b.z, t4b.z) + kl_term(s4b.w, t4b.w);

  // block reduce
  float v = -cosLocal * kCosScale + klLocal * kKlScale;
  #pragma unroll
  for (int off = 32; off > 0; off >>= 1) v += __shfl_down(v, off, 64);
  __shared__ float smem[4];
  const int lane = threadIdx.x & 63;
  const int wid  = threadIdx.x >> 6;
  if (lane == 0) smem[wid] = v;
  __syncthreads();
  if (threadIdx.x == 0) partial[blk] = smem[0] + smem[1] + smem[2] + smem[3];
}

// Single wave: loss = 1 + sum(partial[0..kGrid)). Shuffle-only reduce.
__global__ __launch_bounds__(64) void final_kernel(
    const float* __restrict__ partial, float* __restrict__ out) {
  float acc = 0.f;
  #pragma unroll
  for (int h = 0; h < kGrid / 256; ++h) {   // 8 iterations, float4 each
    const floatx4 v = *reinterpret_cast<const floatx4*>(
        partial + h * 256 + (int)threadIdx.x * 4);
    acc += v.x + v.y + v.z + v.w;
  }
  #pragma unroll
  for (int off = 32; off > 0; off >>= 1) acc += __shfl_down(acc, off, 64);
  if (threadIdx.x == 0) out[0] = 1.f + acc;
}

}  // namespace

extern "C" void kernel_launch(void* const* d_in, const int* in_sizes, int n_in,
                              void* d_out, int out_size, void* d_ws, size_t ws_size,
                              hipStream_t stream) {
  const float* sf = (const float*)d_in[0];
  const float* tf = (const float*)d_in[1];
  const float* sp = (const float*)d_in[2];
  const float* tp = (const float*)d_in[3];
  const int* cur_start = (const int*)d_in[4];
  const int* adj_start = (const int*)d_in[5];
  float* out = (float*)d_out;
  float* partial = (float*)d_ws;  // kGrid * 4 = 8192 bytes

  fused_main<<<kGrid, 256, 0, stream>>>(
      sf, tf, sp, tp, cur_start, adj_start, partial);
  final_kernel<<<1, 64, 0, stream>>>(partial, out);
}